// Round 1
// baseline (841.701 us; speedup 1.0000x reference)
//
#include <hip/hip_runtime.h>
#include <math.h>

#define N_NODES 100000
#define N_EDGES 1600000
#define NFEAT 512
#define NHID 128
#define NCLASS 40

// ============================ CSR build ============================

__global__ void count_kernel(const int* __restrict__ row, int* __restrict__ counts, int E) {
    int e = blockIdx.x * blockDim.x + threadIdx.x;
    if (e < E) atomicAdd(&counts[row[e]], 1);
}

// Exclusive scan, 1024 elements per block (256 threads x 4).
__global__ void scan1_kernel(const int* __restrict__ counts, int* __restrict__ offsets,
                             int* __restrict__ blockSums, int n) {
    __shared__ int sdata[256];
    int t = threadIdx.x;
    int base = blockIdx.x * 1024 + t * 4;
    int v0 = (base + 0 < n) ? counts[base + 0] : 0;
    int v1 = (base + 1 < n) ? counts[base + 1] : 0;
    int v2 = (base + 2 < n) ? counts[base + 2] : 0;
    int v3 = (base + 3 < n) ? counts[base + 3] : 0;
    int tot = v0 + v1 + v2 + v3;
    sdata[t] = tot;
    __syncthreads();
    for (int ofs = 1; ofs < 256; ofs <<= 1) {
        int w = (t >= ofs) ? sdata[t - ofs] : 0;
        __syncthreads();
        sdata[t] += w;
        __syncthreads();
    }
    int excl = sdata[t] - tot;
    if (base + 0 < n) offsets[base + 0] = excl;
    if (base + 1 < n) offsets[base + 1] = excl + v0;
    if (base + 2 < n) offsets[base + 2] = excl + v0 + v1;
    if (base + 3 < n) offsets[base + 3] = excl + v0 + v1 + v2;
    if (t == 255) blockSums[blockIdx.x] = sdata[255];
}

__global__ void scan2_kernel(int* __restrict__ blockSums, int nb) {
    __shared__ int sdata[128];
    int t = threadIdx.x;
    int v = (t < nb) ? blockSums[t] : 0;
    sdata[t] = v;
    __syncthreads();
    for (int ofs = 1; ofs < 128; ofs <<= 1) {
        int w = (t >= ofs) ? sdata[t - ofs] : 0;
        __syncthreads();
        sdata[t] += w;
        __syncthreads();
    }
    if (t < nb) blockSums[t] = sdata[t] - v;   // exclusive
}

__global__ void scan3_kernel(int* __restrict__ offsets, const int* __restrict__ blockSums,
                             int n, int total) {
    int t = threadIdx.x;
    int base = blockIdx.x * 1024 + t * 4;
    int add = blockSums[blockIdx.x];
    #pragma unroll
    for (int j = 0; j < 4; j++)
        if (base + j < n) offsets[base + j] += add;
    if (blockIdx.x == 0 && t == 0) offsets[n] = total;
}

__global__ void fill_kernel(const int* __restrict__ row, const int* __restrict__ col,
                            const float* __restrict__ val, int* __restrict__ cursor,
                            int* __restrict__ csr_col, float* __restrict__ csr_val, int E) {
    int e = blockIdx.x * blockDim.x + threadIdx.x;
    if (e < E) {
        int r = row[e];
        int p = atomicAdd(&cursor[r], 1);
        csr_col[p] = col[e];
        csr_val[p] = val[e];
    }
}

// ============================ GEMM1: support1 = x @ W1 ============================
// [100000 x 512] @ [512 x 128]. Block = 256 threads, 64-row x 128-col tile.
__global__ __launch_bounds__(256)
void gemm1_kernel(const float* __restrict__ x, const float* __restrict__ W1,
                  float* __restrict__ out) {
    __shared__ float As[64][17];    // +1 pad
    __shared__ float Bs[16][128];
    int t = threadIdx.x;
    int row0 = blockIdx.x * 64;
    int tx = t & 31;     // col quad: cols tx*4..tx*4+3
    int ty = t >> 5;     // row octet: rows ty*8..ty*8+7
    float acc[8][4];
    #pragma unroll
    for (int i = 0; i < 8; i++)
        #pragma unroll
        for (int j = 0; j < 4; j++) acc[i][j] = 0.f;

    for (int kc = 0; kc < NFEAT; kc += 16) {
        // stage A: 64 rows x 16 k (each thread one float4)
        {
            int idx = t * 4;
            int ar = idx >> 4;          // 0..63
            int ak = idx & 15;          // 0,4,8,12
            int gr = row0 + ar;
            float4 v = make_float4(0.f, 0.f, 0.f, 0.f);
            if (gr < N_NODES) v = *(const float4*)&x[(size_t)gr * NFEAT + kc + ak];
            As[ar][ak + 0] = v.x; As[ar][ak + 1] = v.y;
            As[ar][ak + 2] = v.z; As[ar][ak + 3] = v.w;
        }
        // stage B: 16 k x 128 n (each thread two float4)
        {
            int brow = t >> 4;           // 0..15
            int bcol = (t & 15) * 8;     // 0..120
            const float* src = &W1[(size_t)(kc + brow) * NHID + bcol];
            float4 v0 = *(const float4*)&src[0];
            float4 v1 = *(const float4*)&src[4];
            *(float4*)&Bs[brow][bcol] = v0;
            *(float4*)&Bs[brow][bcol + 4] = v1;
        }
        __syncthreads();
        #pragma unroll
        for (int k = 0; k < 16; k++) {
            float4 b = *(const float4*)&Bs[k][tx * 4];
            #pragma unroll
            for (int i = 0; i < 8; i++) {
                float a = As[ty * 8 + i][k];
                acc[i][0] += a * b.x; acc[i][1] += a * b.y;
                acc[i][2] += a * b.z; acc[i][3] += a * b.w;
            }
        }
        __syncthreads();
    }
    #pragma unroll
    for (int i = 0; i < 8; i++) {
        int gr = row0 + ty * 8 + i;
        if (gr < N_NODES) {
            float4 v = make_float4(acc[i][0], acc[i][1], acc[i][2], acc[i][3]);
            *(float4*)&out[(size_t)gr * NHID + tx * 4] = v;
        }
    }
}

// ============================ SpMM1 + bias + ReLU ============================
// One block (128 threads) per row; thread f accumulates feature f.
__global__ __launch_bounds__(128)
void spmm1_kernel(const int* __restrict__ offsets, const int* __restrict__ csr_col,
                  const float* __restrict__ csr_val, const float* __restrict__ dense,
                  const float* __restrict__ b1, float* __restrict__ h) {
    int r = blockIdx.x;
    int f = threadIdx.x;
    __shared__ int cols[128];
    __shared__ float vals[128];
    int beg = offsets[r], end = offsets[r + 1];
    float acc = 0.f;
    for (int c0 = beg; c0 < end; c0 += 128) {
        int cnt = min(128, end - c0);
        if (f < cnt) { cols[f] = csr_col[c0 + f]; vals[f] = csr_val[c0 + f]; }
        __syncthreads();
        int i = 0;
        for (; i + 4 <= cnt; i += 4) {
            float a0 = dense[(size_t)cols[i + 0] * NHID + f];
            float a1 = dense[(size_t)cols[i + 1] * NHID + f];
            float a2 = dense[(size_t)cols[i + 2] * NHID + f];
            float a3 = dense[(size_t)cols[i + 3] * NHID + f];
            acc += vals[i + 0] * a0 + vals[i + 1] * a1 + vals[i + 2] * a2 + vals[i + 3] * a3;
        }
        for (; i < cnt; i++)
            acc += vals[i] * dense[(size_t)cols[i] * NHID + f];
        __syncthreads();
    }
    h[(size_t)r * NHID + f] = fmaxf(acc + b1[f], 0.f);
}

// ============================ GEMM2: support2 = h @ W2 ============================
// Block = 256 threads = 4 waves; one wave per row; W2 (20 KB) in LDS.
__global__ __launch_bounds__(256)
void gemm2_kernel(const float* __restrict__ h, const float* __restrict__ W2,
                  float* __restrict__ out) {
    __shared__ float W2s[NHID * NCLASS];  // 5120 floats
    __shared__ float hs[4][NHID];
    int t = threadIdx.x;
    for (int i = t; i < NHID * NCLASS; i += 256) W2s[i] = W2[i];
    int row0 = blockIdx.x * 4;
    {
        int rr = t >> 6;           // wave id
        int cc = (t & 63) * 2;
        float2 v = *(const float2*)&h[(size_t)(row0 + rr) * NHID + cc];
        hs[rr][cc] = v.x; hs[rr][cc + 1] = v.y;
    }
    __syncthreads();
    int w = t >> 6;
    int f = t & 63;
    if (f < NCLASS) {
        float acc = 0.f;
        #pragma unroll 8
        for (int k = 0; k < NHID; k++) acc += hs[w][k] * W2s[k * NCLASS + f];
        out[(size_t)(row0 + w) * NCLASS + f] = acc;
    }
}

// ============================ SpMM2 + bias + log_softmax ============================
// One wave (64 threads) per row; lanes 0..39 own the 40 classes.
__global__ __launch_bounds__(64)
void spmm2_softmax_kernel(const int* __restrict__ offsets, const int* __restrict__ csr_col,
                          const float* __restrict__ csr_val, const float* __restrict__ dense,
                          const float* __restrict__ b2, float* __restrict__ out) {
    int r = blockIdx.x;
    int f = threadIdx.x;   // 0..63
    __shared__ int cols[64];
    __shared__ float vals[64];
    int beg = offsets[r], end = offsets[r + 1];
    float acc = 0.f;
    for (int c0 = beg; c0 < end; c0 += 64) {
        int cnt = min(64, end - c0);
        if (f < cnt) { cols[f] = csr_col[c0 + f]; vals[f] = csr_val[c0 + f]; }
        __syncthreads();
        if (f < NCLASS) {
            int i = 0;
            for (; i + 4 <= cnt; i += 4) {
                float a0 = dense[(size_t)cols[i + 0] * NCLASS + f];
                float a1 = dense[(size_t)cols[i + 1] * NCLASS + f];
                float a2 = dense[(size_t)cols[i + 2] * NCLASS + f];
                float a3 = dense[(size_t)cols[i + 3] * NCLASS + f];
                acc += vals[i + 0] * a0 + vals[i + 1] * a1 + vals[i + 2] * a2 + vals[i + 3] * a3;
            }
            for (; i < cnt; i++)
                acc += vals[i] * dense[(size_t)cols[i] * NCLASS + f];
        }
        __syncthreads();
    }
    float logit = (f < NCLASS) ? (acc + b2[f]) : -INFINITY;
    float m = logit;
    #pragma unroll
    for (int o = 32; o >= 1; o >>= 1) m = fmaxf(m, __shfl_xor(m, o, 64));
    float e = (f < NCLASS) ? __expf(logit - m) : 0.f;
    float s = e;
    #pragma unroll
    for (int o = 32; o >= 1; o >>= 1) s += __shfl_xor(s, o, 64);
    if (f < NCLASS) out[(size_t)r * NCLASS + f] = logit - m - __logf(s);
}

// ============================ launch ============================

extern "C" void kernel_launch(void* const* d_in, const int* in_sizes, int n_in,
                              void* d_out, int out_size, void* d_ws, size_t ws_size,
                              hipStream_t stream) {
    const float* x       = (const float*)d_in[0];
    const int*   adj_row = (const int*)d_in[1];
    const int*   adj_col = (const int*)d_in[2];
    const float* adj_val = (const float*)d_in[3];
    const float* W1      = (const float*)d_in[4];
    const float* b1      = (const float*)d_in[5];
    const float* W2      = (const float*)d_in[6];
    const float* b2      = (const float*)d_in[7];
    float* out = (float*)d_out;

    char* ws = (char*)d_ws;
    size_t off = 0;
    auto alloc = [&](size_t bytes) -> void* {
        void* p = ws + off;
        off += bytes;
        off = (off + 255) & ~(size_t)255;
        return p;
    };
    float* support1 = (float*)alloc((size_t)N_NODES * NHID * 4);     // 51.2 MB
    float* h        = (float*)alloc((size_t)N_NODES * NHID * 4);     // 51.2 MB
    float* support2 = (float*)alloc((size_t)N_NODES * NCLASS * 4);   // 16 MB
    int*   offsets  = (int*)alloc((size_t)(N_NODES + 1) * 4);
    int*   cursor   = (int*)alloc((size_t)N_NODES * 4);              // doubles as counts
    int*   blockSums= (int*)alloc(1024 * 4);
    int*   csr_col  = (int*)alloc((size_t)N_EDGES * 4);
    float* csr_val  = (float*)alloc((size_t)N_EDGES * 4);

    // --- CSR build ---
    hipMemsetAsync(cursor, 0, (size_t)N_NODES * sizeof(int), stream);
    count_kernel<<<(N_EDGES + 255) / 256, 256, 0, stream>>>(adj_row, cursor, N_EDGES);
    int nblk = (N_NODES + 1023) / 1024;   // 98
    scan1_kernel<<<nblk, 256, 0, stream>>>(cursor, offsets, blockSums, N_NODES);
    scan2_kernel<<<1, 128, 0, stream>>>(blockSums, nblk);
    scan3_kernel<<<nblk, 256, 0, stream>>>(offsets, blockSums, N_NODES, N_EDGES);
    hipMemcpyAsync(cursor, offsets, (size_t)N_NODES * sizeof(int),
                   hipMemcpyDeviceToDevice, stream);
    fill_kernel<<<(N_EDGES + 255) / 256, 256, 0, stream>>>(adj_row, adj_col, adj_val,
                                                           cursor, csr_col, csr_val, N_EDGES);
    // --- layer 1 ---
    gemm1_kernel<<<(N_NODES + 63) / 64, 256, 0, stream>>>(x, W1, support1);
    spmm1_kernel<<<N_NODES, 128, 0, stream>>>(offsets, csr_col, csr_val, support1, b1, h);
    // --- layer 2 ---
    gemm2_kernel<<<N_NODES / 4, 256, 0, stream>>>(h, W2, support2);
    spmm2_softmax_kernel<<<N_NODES, 64, 0, stream>>>(offsets, csr_col, csr_val, support2, b2, out);
}

// Round 2
// 729.696 us; speedup vs baseline: 1.1535x; 1.1535x over previous
//
#include <hip/hip_runtime.h>
#include <math.h>

#define N_NODES 100000
#define N_EDGES 1600000
#define NFEAT 512
#define NHID 128
#define NCLASS 40

typedef __attribute__((ext_vector_type(8))) short short8;
typedef __attribute__((ext_vector_type(4))) float floatx4;

__device__ __forceinline__ short f2bf(float f) {
    union { float f; unsigned u; } v; v.f = f;
    unsigned r = v.u + 0x7FFFu + ((v.u >> 16) & 1u);   // round-to-nearest-even
    return (short)(r >> 16);
}
__device__ __forceinline__ float bf2f(unsigned short u) {
    union { unsigned u; float f; } v; v.u = ((unsigned)u) << 16;
    return v.f;
}

// ============================ CSR build ============================

__global__ void count_kernel(const int* __restrict__ row, int* __restrict__ counts, int E) {
    int e = blockIdx.x * blockDim.x + threadIdx.x;
    if (e < E) atomicAdd(&counts[row[e]], 1);
}

__global__ void scan1_kernel(const int* __restrict__ counts, int* __restrict__ offsets,
                             int* __restrict__ blockSums, int n) {
    __shared__ int sdata[256];
    int t = threadIdx.x;
    int base = blockIdx.x * 1024 + t * 4;
    int v0 = (base + 0 < n) ? counts[base + 0] : 0;
    int v1 = (base + 1 < n) ? counts[base + 1] : 0;
    int v2 = (base + 2 < n) ? counts[base + 2] : 0;
    int v3 = (base + 3 < n) ? counts[base + 3] : 0;
    int tot = v0 + v1 + v2 + v3;
    sdata[t] = tot;
    __syncthreads();
    for (int ofs = 1; ofs < 256; ofs <<= 1) {
        int w = (t >= ofs) ? sdata[t - ofs] : 0;
        __syncthreads();
        sdata[t] += w;
        __syncthreads();
    }
    int excl = sdata[t] - tot;
    if (base + 0 < n) offsets[base + 0] = excl;
    if (base + 1 < n) offsets[base + 1] = excl + v0;
    if (base + 2 < n) offsets[base + 2] = excl + v0 + v1;
    if (base + 3 < n) offsets[base + 3] = excl + v0 + v1 + v2;
    if (t == 255) blockSums[blockIdx.x] = sdata[255];
}

__global__ void scan2_kernel(int* __restrict__ blockSums, int nb) {
    __shared__ int sdata[128];
    int t = threadIdx.x;
    int v = (t < nb) ? blockSums[t] : 0;
    sdata[t] = v;
    __syncthreads();
    for (int ofs = 1; ofs < 128; ofs <<= 1) {
        int w = (t >= ofs) ? sdata[t - ofs] : 0;
        __syncthreads();
        sdata[t] += w;
        __syncthreads();
    }
    if (t < nb) blockSums[t] = sdata[t] - v;
}

__global__ void scan3_kernel(int* __restrict__ offsets, const int* __restrict__ blockSums,
                             int n, int total) {
    int t = threadIdx.x;
    int base = blockIdx.x * 1024 + t * 4;
    int add = blockSums[blockIdx.x];
    #pragma unroll
    for (int j = 0; j < 4; j++)
        if (base + j < n) offsets[base + j] += add;
    if (blockIdx.x == 0 && t == 0) offsets[n] = total;
}

__global__ void fill_kernel(const int* __restrict__ row, const int* __restrict__ col,
                            const float* __restrict__ val, int* __restrict__ cursor,
                            int2* __restrict__ csr, int E) {
    int e = blockIdx.x * blockDim.x + threadIdx.x;
    if (e < E) {
        int r = row[e];
        int p = atomicAdd(&cursor[r], 1);
        csr[p] = make_int2(col[e], __float_as_int(val[e]));
    }
}

// ============================ W1 transpose+convert: W1T[n][k] bf16 ============
__global__ void convert_W1_kernel(const float* __restrict__ W1, unsigned short* __restrict__ W1T) {
    int i = blockIdx.x * 256 + threadIdx.x;       // 65536 total
    int k = i >> 7, n = i & 127;                  // W1 is [512][128]
    W1T[(size_t)n * NFEAT + k] = (unsigned short)f2bf(W1[i]);
}

// ============================ GEMM1: support1 = bf16(x @ W1) ==================
// LDS-free MFMA. Block = 256 thr = 4 waves in 2x2; block tile 128 rows x 128 cols.
// Wave computes 64x64 via 4x4 grid of 16x16x32 bf16 MFMA.
__global__ __launch_bounds__(256)
void gemm1_kernel(const float* __restrict__ x, const unsigned short* __restrict__ W1T,
                  unsigned short* __restrict__ out) {
    int t = threadIdx.x;
    int w = t >> 6, l = t & 63;
    int wr = w >> 1, wc = w & 1;
    int lane16 = l & 15, quad = l >> 4;
    int rowBase = blockIdx.x * 128 + wr * 64;
    int colBase = wc * 64;

    floatx4 acc[4][4];
    #pragma unroll
    for (int i = 0; i < 4; i++)
        #pragma unroll
        for (int j = 0; j < 4; j++) acc[i][j] = (floatx4){0.f, 0.f, 0.f, 0.f};

    for (int kc = 0; kc < NFEAT; kc += 32) {
        short8 bfr[4];
        #pragma unroll
        for (int nt = 0; nt < 4; nt++) {
            const unsigned short* bp =
                W1T + (size_t)(colBase + nt * 16 + lane16) * NFEAT + kc + quad * 8;
            bfr[nt] = *(const short8*)bp;           // 16B aligned
        }
        short8 afr[4];
        #pragma unroll
        for (int mt = 0; mt < 4; mt++) {
            int gr = rowBase + mt * 16 + lane16;
            if (gr >= N_NODES) gr = N_NODES - 1;    // safe clamp for loads
            const float* ap = x + (size_t)gr * NFEAT + kc + quad * 8;
            float4 v0 = *(const float4*)ap;
            float4 v1 = *(const float4*)(ap + 4);
            short8 av;
            av[0] = f2bf(v0.x); av[1] = f2bf(v0.y); av[2] = f2bf(v0.z); av[3] = f2bf(v0.w);
            av[4] = f2bf(v1.x); av[5] = f2bf(v1.y); av[6] = f2bf(v1.z); av[7] = f2bf(v1.w);
            afr[mt] = av;
        }
        #pragma unroll
        for (int mt = 0; mt < 4; mt++)
            #pragma unroll
            for (int nt = 0; nt < 4; nt++)
                acc[mt][nt] = __builtin_amdgcn_mfma_f32_16x16x32_bf16(
                    afr[mt], bfr[nt], acc[mt][nt], 0, 0, 0);
    }
    // C/D layout: col = lane&15, row = quad*4 + reg
    #pragma unroll
    for (int mt = 0; mt < 4; mt++) {
        #pragma unroll
        for (int r = 0; r < 4; r++) {
            int gr = rowBase + mt * 16 + quad * 4 + r;
            if (gr < N_NODES) {
                #pragma unroll
                for (int nt = 0; nt < 4; nt++)
                    out[(size_t)gr * NHID + colBase + nt * 16 + lane16] =
                        (unsigned short)f2bf(acc[mt][nt][r]);
            }
        }
    }
}

// ============================ SpMM1 + bias + ReLU =============================
// Block = 256 thr = 4 waves; one wave per row; lane handles features 2l, 2l+1.
__global__ __launch_bounds__(256)
void spmm1_kernel(const int* __restrict__ offsets, const int2* __restrict__ csr,
                  const unsigned short* __restrict__ dense, const float* __restrict__ b1,
                  unsigned short* __restrict__ h) {
    int r = blockIdx.x * 4 + (threadIdx.x >> 6);
    int l = threadIdx.x & 63;
    int beg = offsets[r], end = offsets[r + 1];
    float acc0 = 0.f, acc1 = 0.f;
    for (int c0 = beg; c0 < end; c0 += 64) {
        int cnt = min(64, end - c0);
        int2 pk = (l < cnt) ? csr[c0 + l] : make_int2(0, 0);
        int j = 0;
        for (; j + 4 <= cnt; j += 4) {
            int cA = __shfl(pk.x, j + 0), cB = __shfl(pk.x, j + 1);
            int cC = __shfl(pk.x, j + 2), cD = __shfl(pk.x, j + 3);
            float vA = __int_as_float(__shfl(pk.y, j + 0));
            float vB = __int_as_float(__shfl(pk.y, j + 1));
            float vC = __int_as_float(__shfl(pk.y, j + 2));
            float vD = __int_as_float(__shfl(pk.y, j + 3));
            unsigned dA = *(const unsigned*)&dense[(size_t)cA * NHID + l * 2];
            unsigned dB = *(const unsigned*)&dense[(size_t)cB * NHID + l * 2];
            unsigned dC = *(const unsigned*)&dense[(size_t)cC * NHID + l * 2];
            unsigned dD = *(const unsigned*)&dense[(size_t)cD * NHID + l * 2];
            acc0 += vA * bf2f((unsigned short)dA) + vB * bf2f((unsigned short)dB)
                  + vC * bf2f((unsigned short)dC) + vD * bf2f((unsigned short)dD);
            acc1 += vA * bf2f((unsigned short)(dA >> 16)) + vB * bf2f((unsigned short)(dB >> 16))
                  + vC * bf2f((unsigned short)(dC >> 16)) + vD * bf2f((unsigned short)(dD >> 16));
        }
        for (; j < cnt; j++) {
            int c = __shfl(pk.x, j);
            float v = __int_as_float(__shfl(pk.y, j));
            unsigned d = *(const unsigned*)&dense[(size_t)c * NHID + l * 2];
            acc0 += v * bf2f((unsigned short)d);
            acc1 += v * bf2f((unsigned short)(d >> 16));
        }
    }
    float r0 = fmaxf(acc0 + b1[l * 2 + 0], 0.f);
    float r1 = fmaxf(acc1 + b1[l * 2 + 1], 0.f);
    unsigned packed = ((unsigned)(unsigned short)f2bf(r0)) |
                      (((unsigned)(unsigned short)f2bf(r1)) << 16);
    *(unsigned*)&h[(size_t)r * NHID + l * 2] = packed;
}

// ============================ GEMM2: support2 = bf16(h @ W2) ==================
__global__ __launch_bounds__(256)
void gemm2_kernel(const unsigned short* __restrict__ h, const float* __restrict__ W2,
                  unsigned short* __restrict__ out) {
    __shared__ float W2s[NHID * NCLASS];   // 5120 floats
    __shared__ float hs[4][NHID];
    int t = threadIdx.x;
    for (int i = t; i < NHID * NCLASS; i += 256) W2s[i] = W2[i];
    int row0 = blockIdx.x * 4;
    int rr = t >> 6, l = t & 63;
    {
        unsigned d = *(const unsigned*)&h[(size_t)(row0 + rr) * NHID + l * 2];
        hs[rr][l * 2 + 0] = bf2f((unsigned short)d);
        hs[rr][l * 2 + 1] = bf2f((unsigned short)(d >> 16));
    }
    __syncthreads();
    if (l < NCLASS) {
        float acc = 0.f;
        #pragma unroll 8
        for (int k = 0; k < NHID; k++) acc += hs[rr][k] * W2s[k * NCLASS + l];
        out[(size_t)(row0 + rr) * NCLASS + l] = (unsigned short)f2bf(acc);
    }
}

// ============================ SpMM2 + bias + log_softmax ======================
__global__ __launch_bounds__(256)
void spmm2_kernel(const int* __restrict__ offsets, const int2* __restrict__ csr,
                  const unsigned short* __restrict__ dense, const float* __restrict__ b2,
                  float* __restrict__ out) {
    int r = blockIdx.x * 4 + (threadIdx.x >> 6);
    int l = threadIdx.x & 63;
    int beg = offsets[r], end = offsets[r + 1];
    float acc = 0.f;
    for (int c0 = beg; c0 < end; c0 += 64) {
        int cnt = min(64, end - c0);
        int2 pk = (l < cnt) ? csr[c0 + l] : make_int2(0, 0);
        int j = 0;
        for (; j + 4 <= cnt; j += 4) {
            int cA = __shfl(pk.x, j + 0), cB = __shfl(pk.x, j + 1);
            int cC = __shfl(pk.x, j + 2), cD = __shfl(pk.x, j + 3);
            float vA = __int_as_float(__shfl(pk.y, j + 0));
            float vB = __int_as_float(__shfl(pk.y, j + 1));
            float vC = __int_as_float(__shfl(pk.y, j + 2));
            float vD = __int_as_float(__shfl(pk.y, j + 3));
            if (l < NCLASS) {
                float fA = bf2f(dense[(size_t)cA * NCLASS + l]);
                float fB = bf2f(dense[(size_t)cB * NCLASS + l]);
                float fC = bf2f(dense[(size_t)cC * NCLASS + l]);
                float fD = bf2f(dense[(size_t)cD * NCLASS + l]);
                acc += vA * fA + vB * fB + vC * fC + vD * fD;
            }
        }
        for (; j < cnt; j++) {
            int c = __shfl(pk.x, j);
            float v = __int_as_float(__shfl(pk.y, j));
            if (l < NCLASS) acc += v * bf2f(dense[(size_t)c * NCLASS + l]);
        }
    }
    float logit = (l < NCLASS) ? (acc + b2[l]) : -INFINITY;
    float m = logit;
    #pragma unroll
    for (int o = 32; o >= 1; o >>= 1) m = fmaxf(m, __shfl_xor(m, o, 64));
    float e = (l < NCLASS) ? __expf(logit - m) : 0.f;
    float s = e;
    #pragma unroll
    for (int o = 32; o >= 1; o >>= 1) s += __shfl_xor(s, o, 64);
    if (l < NCLASS) out[(size_t)r * NCLASS + l] = logit - m - __logf(s);
}

// ============================ launch ============================

extern "C" void kernel_launch(void* const* d_in, const int* in_sizes, int n_in,
                              void* d_out, int out_size, void* d_ws, size_t ws_size,
                              hipStream_t stream) {
    const float* x       = (const float*)d_in[0];
    const int*   adj_row = (const int*)d_in[1];
    const int*   adj_col = (const int*)d_in[2];
    const float* adj_val = (const float*)d_in[3];
    const float* W1      = (const float*)d_in[4];
    const float* b1      = (const float*)d_in[5];
    const float* W2      = (const float*)d_in[6];
    const float* b2      = (const float*)d_in[7];
    float* out = (float*)d_out;

    char* ws = (char*)d_ws;
    size_t off = 0;
    auto alloc = [&](size_t bytes) -> void* {
        void* p = ws + off;
        off += bytes;
        off = (off + 255) & ~(size_t)255;
        return p;
    };
    unsigned short* support1 = (unsigned short*)alloc((size_t)N_NODES * NHID * 2);   // 25.6 MB
    unsigned short* h        = (unsigned short*)alloc((size_t)N_NODES * NHID * 2);   // 25.6 MB
    unsigned short* support2 = (unsigned short*)alloc((size_t)N_NODES * NCLASS * 2); // 8 MB
    unsigned short* W1T      = (unsigned short*)alloc((size_t)NFEAT * NHID * 2);     // 128 KB
    int*   offsets  = (int*)alloc((size_t)(N_NODES + 4) * 4);
    int*   cursor   = (int*)alloc((size_t)N_NODES * 4);
    int*   blockSums= (int*)alloc(1024 * 4);
    int2*  csr      = (int2*)alloc((size_t)N_EDGES * 8);                             // 12.8 MB

    // --- CSR build + W1 convert ---
    hipMemsetAsync(cursor, 0, (size_t)N_NODES * sizeof(int), stream);
    convert_W1_kernel<<<(NFEAT * NHID) / 256, 256, 0, stream>>>(W1, W1T);
    count_kernel<<<(N_EDGES + 255) / 256, 256, 0, stream>>>(adj_row, cursor, N_EDGES);
    int nblk = (N_NODES + 1023) / 1024;   // 98
    scan1_kernel<<<nblk, 256, 0, stream>>>(cursor, offsets, blockSums, N_NODES);
    scan2_kernel<<<1, 128, 0, stream>>>(blockSums, nblk);
    scan3_kernel<<<nblk, 256, 0, stream>>>(offsets, blockSums, N_NODES, N_EDGES);
    hipMemcpyAsync(cursor, offsets, (size_t)N_NODES * sizeof(int),
                   hipMemcpyDeviceToDevice, stream);
    fill_kernel<<<(N_EDGES + 255) / 256, 256, 0, stream>>>(adj_row, adj_col, adj_val,
                                                           cursor, csr, N_EDGES);
    // --- layer 1 ---
    gemm1_kernel<<<(N_NODES + 127) / 128, 256, 0, stream>>>(x, W1T, support1);
    spmm1_kernel<<<N_NODES / 4, 256, 0, stream>>>(offsets, csr, support1, b1, h);
    // --- layer 2 ---
    gemm2_kernel<<<N_NODES / 4, 256, 0, stream>>>(h, W2, support2);
    spmm2_kernel<<<N_NODES / 4, 256, 0, stream>>>(offsets, csr, support2, b2, out);
}

// Round 3
// 689.288 us; speedup vs baseline: 1.2211x; 1.0586x over previous
//
#include <hip/hip_runtime.h>
#include <hip/hip_bf16.h>
#include <math.h>

#define N_NODES 100000
#define N_EDGES 1600000
#define NFEAT 512
#define NHID 128
#define NCLASS 40
#define GEMM1_BLOCKS ((N_NODES + 255) / 256)   // 391
#define COUNT_BLOCKS ((N_EDGES + 255) / 256)   // 6250
#define CPAD 16                                // one counter per 64B line

typedef __attribute__((ext_vector_type(8))) short short8;
typedef __attribute__((ext_vector_type(4))) float floatx4;

__device__ __forceinline__ short f2bf(float f) {
    union { float f; unsigned u; } v; v.f = f;
    unsigned r = v.u + 0x7FFFu + ((v.u >> 16) & 1u);
    return (short)(r >> 16);
}
__device__ __forceinline__ float bf2f(unsigned short u) {
    union { unsigned u; float f; } v; v.u = ((unsigned)u) << 16;
    return v.f;
}
__device__ __forceinline__ unsigned pk2bf(float a, float b) {
    __hip_bfloat162 t = __float22bfloat162_rn(make_float2(a, b));
    union { __hip_bfloat162 h; unsigned u; } v; v.h = t;
    return v.u;
}

// ============================ W1 transpose+convert: W1T[n][k] bf16 ============
__global__ void convert_W1_kernel(const float* __restrict__ W1, unsigned short* __restrict__ W1T) {
    int i = blockIdx.x * 256 + threadIdx.x;       // 65536 total
    int k = i >> 7, n = i & 127;                  // W1 is [512][128]
    W1T[(size_t)n * NFEAT + k] = (unsigned short)f2bf(W1[i]);
}

// ============ Fused: GEMM1 (support1 = bf16(x @ W1)) + edge count ============
// gemm blocks: 256 thr = 4 row-stacked waves; wave = 64 rows x 128 cols
// (4x8 grid of 16x16x32 MFMA). A (x rows) read exactly once. No LDS.
// count blocks: 1 edge/thread, atomicAdd to line-padded counters.
__global__ __launch_bounds__(256, 2)
void fusedA_kernel(const float* __restrict__ x, const unsigned short* __restrict__ W1T,
                   unsigned short* __restrict__ out,
                   const int* __restrict__ adj_row, int* __restrict__ countsPad) {
    if (blockIdx.x >= GEMM1_BLOCKS) {
        int e = (blockIdx.x - GEMM1_BLOCKS) * 256 + threadIdx.x;
        if (e < N_EDGES) atomicAdd(&countsPad[(size_t)adj_row[e] * CPAD], 1);
        return;
    }
    int t = threadIdx.x;
    int w = t >> 6, l = t & 63;
    int lane16 = l & 15, quad = l >> 4;
    int rowBase = blockIdx.x * 256 + w * 64;

    floatx4 acc[4][8];
    #pragma unroll
    for (int i = 0; i < 4; i++)
        #pragma unroll
        for (int j = 0; j < 8; j++) acc[i][j] = (floatx4){0.f, 0.f, 0.f, 0.f};

    for (int kc = 0; kc < NFEAT; kc += 32) {
        short8 bfr[8];
        #pragma unroll
        for (int nt = 0; nt < 8; nt++) {
            const unsigned short* bp =
                W1T + (size_t)(nt * 16 + lane16) * NFEAT + kc + quad * 8;
            bfr[nt] = *(const short8*)bp;
        }
        short8 afr[4];
        #pragma unroll
        for (int mt = 0; mt < 4; mt++) {
            int gr = rowBase + mt * 16 + lane16;
            if (gr >= N_NODES) gr = N_NODES - 1;     // safe clamp (stores guarded)
            const float* ap = x + (size_t)gr * NFEAT + kc + quad * 8;
            float4 v0 = *(const float4*)ap;
            float4 v1 = *(const float4*)(ap + 4);
            union { short8 s; unsigned u[4]; } av;
            av.u[0] = pk2bf(v0.x, v0.y);
            av.u[1] = pk2bf(v0.z, v0.w);
            av.u[2] = pk2bf(v1.x, v1.y);
            av.u[3] = pk2bf(v1.z, v1.w);
            afr[mt] = av.s;
        }
        #pragma unroll
        for (int mt = 0; mt < 4; mt++)
            #pragma unroll
            for (int nt = 0; nt < 8; nt++)
                acc[mt][nt] = __builtin_amdgcn_mfma_f32_16x16x32_bf16(
                    afr[mt], bfr[nt], acc[mt][nt], 0, 0, 0);
    }
    // C/D layout: col = lane&15, row = quad*4 + reg
    #pragma unroll
    for (int mt = 0; mt < 4; mt++) {
        #pragma unroll
        for (int r = 0; r < 4; r++) {
            int gr = rowBase + mt * 16 + quad * 4 + r;
            if (gr < N_NODES) {
                #pragma unroll
                for (int nt = 0; nt < 8; nt++)
                    out[(size_t)gr * NHID + nt * 16 + lane16] =
                        (unsigned short)f2bf(acc[mt][nt][r]);
            }
        }
    }
}

// ============================ scans (exclusive prefix over counts) ============
__global__ void scan1_kernel(const int* __restrict__ countsPad, int* __restrict__ offsets,
                             int* __restrict__ blockSums, int n) {
    __shared__ int sdata[256];
    int t = threadIdx.x;
    int base = blockIdx.x * 1024 + t * 4;
    int v0 = (base + 0 < n) ? countsPad[(size_t)(base + 0) * CPAD] : 0;
    int v1 = (base + 1 < n) ? countsPad[(size_t)(base + 1) * CPAD] : 0;
    int v2 = (base + 2 < n) ? countsPad[(size_t)(base + 2) * CPAD] : 0;
    int v3 = (base + 3 < n) ? countsPad[(size_t)(base + 3) * CPAD] : 0;
    int tot = v0 + v1 + v2 + v3;
    sdata[t] = tot;
    __syncthreads();
    for (int ofs = 1; ofs < 256; ofs <<= 1) {
        int w = (t >= ofs) ? sdata[t - ofs] : 0;
        __syncthreads();
        sdata[t] += w;
        __syncthreads();
    }
    int excl = sdata[t] - tot;
    if (base + 0 < n) offsets[base + 0] = excl;
    if (base + 1 < n) offsets[base + 1] = excl + v0;
    if (base + 2 < n) offsets[base + 2] = excl + v0 + v1;
    if (base + 3 < n) offsets[base + 3] = excl + v0 + v1 + v2;
    if (t == 255) blockSums[blockIdx.x] = sdata[255];
}

__global__ void scan2_kernel(int* __restrict__ blockSums, int nb) {
    __shared__ int sdata[128];
    int t = threadIdx.x;
    int v = (t < nb) ? blockSums[t] : 0;
    sdata[t] = v;
    __syncthreads();
    for (int ofs = 1; ofs < 128; ofs <<= 1) {
        int w = (t >= ofs) ? sdata[t - ofs] : 0;
        __syncthreads();
        sdata[t] += w;
        __syncthreads();
    }
    if (t < nb) blockSums[t] = sdata[t] - v;
}

// adds block offset; seeds padded cursor with final row offsets (replaces memcpy)
__global__ void scan3_kernel(int* __restrict__ offsets, const int* __restrict__ blockSums,
                             int* __restrict__ cursorPad, int n, int total) {
    int t = threadIdx.x;
    int base = blockIdx.x * 1024 + t * 4;
    int add = blockSums[blockIdx.x];
    #pragma unroll
    for (int j = 0; j < 4; j++)
        if (base + j < n) {
            int v = offsets[base + j] + add;
            offsets[base + j] = v;
            cursorPad[(size_t)(base + j) * CPAD] = v;
        }
    if (blockIdx.x == 0 && t == 0) offsets[n] = total;
}

__global__ void fill_kernel(const int* __restrict__ row, const int* __restrict__ col,
                            const float* __restrict__ val, int* __restrict__ cursorPad,
                            int2* __restrict__ csr, int E) {
    int e = blockIdx.x * blockDim.x + threadIdx.x;
    if (e < E) {
        int r = row[e];
        int p = atomicAdd(&cursorPad[(size_t)r * CPAD], 1);
        csr[p] = make_int2(col[e], __float_as_int(val[e]));
    }
}

// ============================ SpMM1 + bias + ReLU =============================
__global__ __launch_bounds__(256)
void spmm1_kernel(const int* __restrict__ offsets, const int2* __restrict__ csr,
                  const unsigned short* __restrict__ dense, const float* __restrict__ b1,
                  unsigned short* __restrict__ h) {
    int r = blockIdx.x * 4 + (threadIdx.x >> 6);
    int l = threadIdx.x & 63;
    int beg = offsets[r], end = offsets[r + 1];
    float acc0 = 0.f, acc1 = 0.f;
    for (int c0 = beg; c0 < end; c0 += 64) {
        int cnt = min(64, end - c0);
        int2 pk = (l < cnt) ? csr[c0 + l] : make_int2(0, 0);
        int j = 0;
        for (; j + 4 <= cnt; j += 4) {
            int cA = __shfl(pk.x, j + 0), cB = __shfl(pk.x, j + 1);
            int cC = __shfl(pk.x, j + 2), cD = __shfl(pk.x, j + 3);
            float vA = __int_as_float(__shfl(pk.y, j + 0));
            float vB = __int_as_float(__shfl(pk.y, j + 1));
            float vC = __int_as_float(__shfl(pk.y, j + 2));
            float vD = __int_as_float(__shfl(pk.y, j + 3));
            unsigned dA = *(const unsigned*)&dense[(size_t)cA * NHID + l * 2];
            unsigned dB = *(const unsigned*)&dense[(size_t)cB * NHID + l * 2];
            unsigned dC = *(const unsigned*)&dense[(size_t)cC * NHID + l * 2];
            unsigned dD = *(const unsigned*)&dense[(size_t)cD * NHID + l * 2];
            acc0 += vA * bf2f((unsigned short)dA) + vB * bf2f((unsigned short)dB)
                  + vC * bf2f((unsigned short)dC) + vD * bf2f((unsigned short)dD);
            acc1 += vA * bf2f((unsigned short)(dA >> 16)) + vB * bf2f((unsigned short)(dB >> 16))
                  + vC * bf2f((unsigned short)(dC >> 16)) + vD * bf2f((unsigned short)(dD >> 16));
        }
        for (; j < cnt; j++) {
            int c = __shfl(pk.x, j);
            float v = __int_as_float(__shfl(pk.y, j));
            unsigned d = *(const unsigned*)&dense[(size_t)c * NHID + l * 2];
            acc0 += v * bf2f((unsigned short)d);
            acc1 += v * bf2f((unsigned short)(d >> 16));
        }
    }
    float r0 = fmaxf(acc0 + b1[l * 2 + 0], 0.f);
    float r1 = fmaxf(acc1 + b1[l * 2 + 1], 0.f);
    unsigned packed = ((unsigned)(unsigned short)f2bf(r0)) |
                      (((unsigned)(unsigned short)f2bf(r1)) << 16);
    *(unsigned*)&h[(size_t)r * NHID + l * 2] = packed;
}

// ============================ GEMM2: support2 = bf16(h @ W2) ==================
__global__ __launch_bounds__(256)
void gemm2_kernel(const unsigned short* __restrict__ h, const float* __restrict__ W2,
                  unsigned short* __restrict__ out) {
    __shared__ float W2s[NHID * NCLASS];
    __shared__ float hs[4][NHID];
    int t = threadIdx.x;
    for (int i = t; i < NHID * NCLASS; i += 256) W2s[i] = W2[i];
    int row0 = blockIdx.x * 4;
    int rr = t >> 6, l = t & 63;
    {
        unsigned d = *(const unsigned*)&h[(size_t)(row0 + rr) * NHID + l * 2];
        hs[rr][l * 2 + 0] = bf2f((unsigned short)d);
        hs[rr][l * 2 + 1] = bf2f((unsigned short)(d >> 16));
    }
    __syncthreads();
    if (l < NCLASS) {
        float acc = 0.f;
        #pragma unroll 8
        for (int k = 0; k < NHID; k++) acc += hs[rr][k] * W2s[k * NCLASS + l];
        out[(size_t)(row0 + rr) * NCLASS + l] = (unsigned short)f2bf(acc);
    }
}

// ============================ SpMM2 + bias + log_softmax ======================
__global__ __launch_bounds__(256)
void spmm2_kernel(const int* __restrict__ offsets, const int2* __restrict__ csr,
                  const unsigned short* __restrict__ dense, const float* __restrict__ b2,
                  float* __restrict__ out) {
    int r = blockIdx.x * 4 + (threadIdx.x >> 6);
    int l = threadIdx.x & 63;
    int beg = offsets[r], end = offsets[r + 1];
    float acc = 0.f;
    for (int c0 = beg; c0 < end; c0 += 64) {
        int cnt = min(64, end - c0);
        int2 pk = (l < cnt) ? csr[c0 + l] : make_int2(0, 0);
        int j = 0;
        for (; j + 4 <= cnt; j += 4) {
            int cA = __shfl(pk.x, j + 0), cB = __shfl(pk.x, j + 1);
            int cC = __shfl(pk.x, j + 2), cD = __shfl(pk.x, j + 3);
            float vA = __int_as_float(__shfl(pk.y, j + 0));
            float vB = __int_as_float(__shfl(pk.y, j + 1));
            float vC = __int_as_float(__shfl(pk.y, j + 2));
            float vD = __int_as_float(__shfl(pk.y, j + 3));
            if (l < NCLASS) {
                float fA = bf2f(dense[(size_t)cA * NCLASS + l]);
                float fB = bf2f(dense[(size_t)cB * NCLASS + l]);
                float fC = bf2f(dense[(size_t)cC * NCLASS + l]);
                float fD = bf2f(dense[(size_t)cD * NCLASS + l]);
                acc += vA * fA + vB * fB + vC * fC + vD * fD;
            }
        }
        for (; j < cnt; j++) {
            int c = __shfl(pk.x, j);
            float v = __int_as_float(__shfl(pk.y, j));
            if (l < NCLASS) acc += v * bf2f(dense[(size_t)c * NCLASS + l]);
        }
    }
    float logit = (l < NCLASS) ? (acc + b2[l]) : -INFINITY;
    float m = logit;
    #pragma unroll
    for (int o = 32; o >= 1; o >>= 1) m = fmaxf(m, __shfl_xor(m, o, 64));
    float e = (l < NCLASS) ? __expf(logit - m) : 0.f;
    float s = e;
    #pragma unroll
    for (int o = 32; o >= 1; o >>= 1) s += __shfl_xor(s, o, 64);
    if (l < NCLASS) out[(size_t)r * NCLASS + l] = logit - m - __logf(s);
}

// ============================ launch ============================

extern "C" void kernel_launch(void* const* d_in, const int* in_sizes, int n_in,
                              void* d_out, int out_size, void* d_ws, size_t ws_size,
                              hipStream_t stream) {
    const float* x       = (const float*)d_in[0];
    const int*   adj_row = (const int*)d_in[1];
    const int*   adj_col = (const int*)d_in[2];
    const float* adj_val = (const float*)d_in[3];
    const float* W1      = (const float*)d_in[4];
    const float* b1      = (const float*)d_in[5];
    const float* W2      = (const float*)d_in[6];
    const float* b2      = (const float*)d_in[7];
    float* out = (float*)d_out;

    char* ws = (char*)d_ws;
    size_t off = 0;
    auto alloc = [&](size_t bytes) -> void* {
        void* p = ws + off;
        off += bytes;
        off = (off + 255) & ~(size_t)255;
        return p;
    };
    unsigned short* support1 = (unsigned short*)alloc((size_t)N_NODES * NHID * 2);   // 25.6 MB
    unsigned short* h        = (unsigned short*)alloc((size_t)N_NODES * NHID * 2);   // 25.6 MB
    unsigned short* support2 = (unsigned short*)alloc((size_t)N_NODES * NCLASS * 2); // 8 MB
    unsigned short* W1T      = (unsigned short*)alloc((size_t)NFEAT * NHID * 2);     // 128 KB
    int*   offsets   = (int*)alloc((size_t)(N_NODES + 4) * 4);
    int*   countsPad = (int*)alloc((size_t)N_NODES * CPAD * 4);                      // 6.4 MB
    int*   blockSums = (int*)alloc(1024 * 4);
    int2*  csr       = (int2*)alloc((size_t)N_EDGES * 8);                            // 12.8 MB

    hipMemsetAsync(countsPad, 0, (size_t)N_NODES * CPAD * sizeof(int), stream);
    convert_W1_kernel<<<(NFEAT * NHID) / 256, 256, 0, stream>>>(W1, W1T);
    // fused GEMM1 + edge-count
    fusedA_kernel<<<GEMM1_BLOCKS + COUNT_BLOCKS, 256, 0, stream>>>(
        x, W1T, support1, adj_row, countsPad);
    int nblk = (N_NODES + 1023) / 1024;   // 98
    scan1_kernel<<<nblk, 256, 0, stream>>>(countsPad, offsets, blockSums, N_NODES);
    scan2_kernel<<<1, 128, 0, stream>>>(blockSums, nblk);
    scan3_kernel<<<nblk, 256, 0, stream>>>(offsets, blockSums, countsPad, N_NODES, N_EDGES);
    fill_kernel<<<COUNT_BLOCKS, 256, 0, stream>>>(adj_row, adj_col, adj_val,
                                                  countsPad, csr, N_EDGES);
    spmm1_kernel<<<N_NODES / 4, 256, 0, stream>>>(offsets, csr, support1, b1, h);
    gemm2_kernel<<<N_NODES / 4, 256, 0, stream>>>(h, W2, support2);
    spmm2_kernel<<<N_NODES / 4, 256, 0, stream>>>(offsets, csr, support2, b2, out);
}

// Round 5
// 682.823 us; speedup vs baseline: 1.2327x; 1.0095x over previous
//
#include <hip/hip_runtime.h>
#include <hip/hip_bf16.h>
#include <math.h>

#define N_NODES 100000
#define N_EDGES 1600000
#define NFEAT 512
#define NHID 128
#define NCLASS 40
#define GEMM1_BLOCKS ((N_NODES + 63) / 64)       // 1563: 4 waves x 16 rows
#define COUNT_BLOCKS ((N_EDGES + 1023) / 1024)   // 1563: 256 thr x 4 edges
#define CPAD 16                                  // one counter per 64B line

typedef __attribute__((ext_vector_type(8))) short short8;
typedef __attribute__((ext_vector_type(4))) float floatx4;

__device__ __forceinline__ short f2bf(float f) {
    union { float f; unsigned u; } v; v.f = f;
    unsigned r = v.u + 0x7FFFu + ((v.u >> 16) & 1u);
    return (short)(r >> 16);
}
__device__ __forceinline__ float bf2f(unsigned short u) {
    union { unsigned u; float f; } v; v.u = ((unsigned)u) << 16;
    return v.f;
}
__device__ __forceinline__ unsigned pk2bf(float a, float b) {
    __hip_bfloat162 t = __float22bfloat162_rn(make_float2(a, b));
    union { __hip_bfloat162 h; unsigned u; } v; v.h = t;
    return v.u;
}

// ============================ W1 transpose+convert: W1T[n][k] bf16 ============
__global__ void convert_W1_kernel(const float* __restrict__ W1, unsigned short* __restrict__ W1T) {
    int i = blockIdx.x * 256 + threadIdx.x;       // 65536 total
    int k = i >> 7, n = i & 127;                  // W1 is [512][128]
    W1T[(size_t)n * NFEAT + k] = (unsigned short)f2bf(W1[i]);
}

// ====== Fused: GEMM1 (support1 = bf16(x @ W1)) + edge count w/ rank capture ==
// gemm blocks: 4 waves, each 16 rows x 128 cols (1x8 grid of 16x16x32 MFMA).
// count blocks: 4 edges/thread, atomicAdd to line-padded counters, save rank.
__global__ __launch_bounds__(256)
void fusedA_kernel(const float* __restrict__ x, const unsigned short* __restrict__ W1T,
                   unsigned short* __restrict__ out,
                   const int* __restrict__ adj_row, int* __restrict__ countsPad,
                   unsigned short* __restrict__ ranks) {
    if (blockIdx.x >= GEMM1_BLOCKS) {
        int base = (blockIdx.x - GEMM1_BLOCKS) * 1024 + threadIdx.x;
        int e0 = base, e1 = base + 256, e2 = base + 512, e3 = base + 768;
        int r0 = (e0 < N_EDGES) ? adj_row[e0] : -1;
        int r1 = (e1 < N_EDGES) ? adj_row[e1] : -1;
        int r2 = (e2 < N_EDGES) ? adj_row[e2] : -1;
        int r3 = (e3 < N_EDGES) ? adj_row[e3] : -1;
        if (r0 >= 0) ranks[e0] = (unsigned short)atomicAdd(&countsPad[(size_t)r0 * CPAD], 1);
        if (r1 >= 0) ranks[e1] = (unsigned short)atomicAdd(&countsPad[(size_t)r1 * CPAD], 1);
        if (r2 >= 0) ranks[e2] = (unsigned short)atomicAdd(&countsPad[(size_t)r2 * CPAD], 1);
        if (r3 >= 0) ranks[e3] = (unsigned short)atomicAdd(&countsPad[(size_t)r3 * CPAD], 1);
        return;
    }
    int t = threadIdx.x;
    int w = t >> 6, l = t & 63;
    int lane16 = l & 15, quad = l >> 4;
    int rowBase = blockIdx.x * 64 + w * 16;

    floatx4 acc[8];
    #pragma unroll
    for (int j = 0; j < 8; j++) acc[j] = (floatx4){0.f, 0.f, 0.f, 0.f};

    int gr = rowBase + lane16;
    if (gr >= N_NODES) gr = N_NODES - 1;          // safe clamp (stores guarded)
    const float* aRow = x + (size_t)gr * NFEAT + quad * 8;

    for (int kc = 0; kc < NFEAT; kc += 32) {
        float4 v0 = *(const float4*)(aRow + kc);
        float4 v1 = *(const float4*)(aRow + kc + 4);
        union { short8 s; unsigned u[4]; } av;
        av.u[0] = pk2bf(v0.x, v0.y);
        av.u[1] = pk2bf(v0.z, v0.w);
        av.u[2] = pk2bf(v1.x, v1.y);
        av.u[3] = pk2bf(v1.z, v1.w);
        short8 afr = av.s;
        #pragma unroll
        for (int nt = 0; nt < 8; nt++) {
            const unsigned short* bp =
                W1T + (size_t)(nt * 16 + lane16) * NFEAT + kc + quad * 8;
            short8 bfr = *(const short8*)bp;
            acc[nt] = __builtin_amdgcn_mfma_f32_16x16x32_bf16(afr, bfr, acc[nt], 0, 0, 0);
        }
    }
    // C/D layout: col = lane&15, row = quad*4 + reg
    #pragma unroll
    for (int r = 0; r < 4; r++) {
        int gr2 = rowBase + quad * 4 + r;
        if (gr2 < N_NODES) {
            #pragma unroll
            for (int nt = 0; nt < 8; nt++)
                out[(size_t)gr2 * NHID + nt * 16 + lane16] =
                    (unsigned short)f2bf(acc[nt][r]);
        }
    }
}

// ============================ scans (exclusive prefix over counts) ============
__global__ void scan1_kernel(const int* __restrict__ countsPad, int* __restrict__ offsets,
                             int* __restrict__ blockSums, int n) {
    __shared__ int sdata[256];
    int t = threadIdx.x;
    int base = blockIdx.x * 1024 + t * 4;
    int v0 = (base + 0 < n) ? countsPad[(size_t)(base + 0) * CPAD] : 0;
    int v1 = (base + 1 < n) ? countsPad[(size_t)(base + 1) * CPAD] : 0;
    int v2 = (base + 2 < n) ? countsPad[(size_t)(base + 2) * CPAD] : 0;
    int v3 = (base + 3 < n) ? countsPad[(size_t)(base + 3) * CPAD] : 0;
    int tot = v0 + v1 + v2 + v3;
    sdata[t] = tot;
    __syncthreads();
    for (int ofs = 1; ofs < 256; ofs <<= 1) {
        int w = (t >= ofs) ? sdata[t - ofs] : 0;
        __syncthreads();
        sdata[t] += w;
        __syncthreads();
    }
    int excl = sdata[t] - tot;
    if (base + 0 < n) offsets[base + 0] = excl;
    if (base + 1 < n) offsets[base + 1] = excl + v0;
    if (base + 2 < n) offsets[base + 2] = excl + v0 + v1;
    if (base + 3 < n) offsets[base + 3] = excl + v0 + v1 + v2;
    if (t == 255) blockSums[blockIdx.x] = sdata[255];
}

__global__ void scan2_kernel(int* __restrict__ blockSums, int nb) {
    __shared__ int sdata[128];
    int t = threadIdx.x;
    int v = (t < nb) ? blockSums[t] : 0;
    sdata[t] = v;
    __syncthreads();
    for (int ofs = 1; ofs < 128; ofs <<= 1) {
        int w = (t >= ofs) ? sdata[t - ofs] : 0;
        __syncthreads();
        sdata[t] += w;
        __syncthreads();
    }
    if (t < nb) blockSums[t] = sdata[t] - v;
}

__global__ void scan3_kernel(int* __restrict__ offsets, const int* __restrict__ blockSums,
                             int n, int total) {
    int t = threadIdx.x;
    int base = blockIdx.x * 1024 + t * 4;
    int add = blockSums[blockIdx.x];
    #pragma unroll
    for (int j = 0; j < 4; j++)
        if (base + j < n) offsets[base + j] += add;
    if (blockIdx.x == 0 && t == 0) offsets[n] = total;
}

// ================= fill: NO atomics — position = offset[row] + rank =========
__global__ __launch_bounds__(256)
void fill_kernel(const int* __restrict__ row, const int* __restrict__ col,
                 const float* __restrict__ val, const int* __restrict__ offsets,
                 const unsigned short* __restrict__ ranks, int2* __restrict__ csr) {
    int base = blockIdx.x * 1024 + threadIdx.x;
    #pragma unroll
    for (int i = 0; i < 4; i++) {
        int e = base + i * 256;
        if (e < N_EDGES) {
            int r = row[e];
            int p = offsets[r] + (int)ranks[e];
            csr[p] = make_int2(col[e], __float_as_int(val[e]));
        }
    }
}

// ============================ SpMM1 + bias + ReLU =============================
__global__ __launch_bounds__(256)
void spmm1_kernel(const int* __restrict__ offsets, const int2* __restrict__ csr,
                  const unsigned short* __restrict__ dense, const float* __restrict__ b1,
                  unsigned short* __restrict__ h) {
    int r = blockIdx.x * 4 + (threadIdx.x >> 6);
    int l = threadIdx.x & 63;
    int beg = offsets[r], end = offsets[r + 1];
    float acc0 = 0.f, acc1 = 0.f;
    for (int c0 = beg; c0 < end; c0 += 64) {
        int cnt = min(64, end - c0);
        int2 pk = (l < cnt) ? csr[c0 + l] : make_int2(0, 0);
        int j = 0;
        for (; j + 8 <= cnt; j += 8) {
            unsigned d[8];
            float v[8];
            #pragma unroll
            for (int q = 0; q < 8; q++) {
                int c = __shfl(pk.x, j + q);
                v[q] = __int_as_float(__shfl(pk.y, j + q));
                d[q] = *(const unsigned*)&dense[(size_t)c * NHID + l * 2];
            }
            #pragma unroll
            for (int q = 0; q < 8; q++) {
                acc0 += v[q] * bf2f((unsigned short)d[q]);
                acc1 += v[q] * bf2f((unsigned short)(d[q] >> 16));
            }
        }
        for (; j < cnt; j++) {
            int c = __shfl(pk.x, j);
            float v = __int_as_float(__shfl(pk.y, j));
            unsigned d = *(const unsigned*)&dense[(size_t)c * NHID + l * 2];
            acc0 += v * bf2f((unsigned short)d);
            acc1 += v * bf2f((unsigned short)(d >> 16));
        }
    }
    float r0 = fmaxf(acc0 + b1[l * 2 + 0], 0.f);
    float r1 = fmaxf(acc1 + b1[l * 2 + 1], 0.f);
    *(unsigned*)&h[(size_t)r * NHID + l * 2] = pk2bf(r0, r1);
}

// ================= GEMM2: support2 = bf16(h @ W2), 32 rows/block =============
__global__ __launch_bounds__(256)
void gemm2_kernel(const unsigned short* __restrict__ h, const float* __restrict__ W2,
                  unsigned short* __restrict__ out) {
    __shared__ float W2s[NHID * NCLASS];   // 5120 floats, 20 KB
    __shared__ float hs[32][NHID];         // 16 KB
    int t = threadIdx.x;
    for (int i = t; i < NHID * NCLASS; i += 256) W2s[i] = W2[i];   // 20 strides
    int row0 = blockIdx.x * 32;
    {   // 32 rows x 64 unsigned = 2048 unsigned; 8 per thread
        const unsigned* hsrc = (const unsigned*)(h + (size_t)row0 * NHID);
        #pragma unroll
        for (int j = 0; j < 8; j++) {
            int f = t * 8 + j;          // unsigned index; row = f>>6, c2 = f&63
            unsigned d = hsrc[f];
            hs[f >> 6][(f & 63) * 2 + 0] = bf2f((unsigned short)d);
            hs[f >> 6][(f & 63) * 2 + 1] = bf2f((unsigned short)(d >> 16));
        }
    }
    __syncthreads();
    int w = t >> 6, l = t & 63;
    if (l < NCLASS) {
        float acc[8];
        #pragma unroll
        for (int j = 0; j < 8; j++) acc[j] = 0.f;
        #pragma unroll 4
        for (int k = 0; k < NHID; k++) {
            float wk = W2s[k * NCLASS + l];
            #pragma unroll
            for (int j = 0; j < 8; j++) acc[j] += hs[w * 8 + j][k] * wk;
        }
        #pragma unroll
        for (int j = 0; j < 8; j++)
            out[(size_t)(row0 + w * 8 + j) * NCLASS + l] = (unsigned short)f2bf(acc[j]);
    }
}

// ============================ SpMM2 + bias + log_softmax ======================
__global__ __launch_bounds__(256)
void spmm2_kernel(const int* __restrict__ offsets, const int2* __restrict__ csr,
                  const unsigned short* __restrict__ dense, const float* __restrict__ b2,
                  float* __restrict__ out) {
    int r = blockIdx.x * 4 + (threadIdx.x >> 6);
    int l = threadIdx.x & 63;
    int beg = offsets[r], end = offsets[r + 1];
    float acc = 0.f;
    for (int c0 = beg; c0 < end; c0 += 64) {
        int cnt = min(64, end - c0);
        int2 pk = (l < cnt) ? csr[c0 + l] : make_int2(0, 0);
        int j = 0;
        for (; j + 8 <= cnt; j += 8) {
            float v[8], f[8];
            #pragma unroll
            for (int q = 0; q < 8; q++) {
                int c = __shfl(pk.x, j + q);
                v[q] = __int_as_float(__shfl(pk.y, j + q));
                f[q] = (l < NCLASS) ? bf2f(dense[(size_t)c * NCLASS + l]) : 0.f;
            }
            #pragma unroll
            for (int q = 0; q < 8; q++) acc += v[q] * f[q];
        }
        for (; j < cnt; j++) {
            int c = __shfl(pk.x, j);
            float v = __int_as_float(__shfl(pk.y, j));
            if (l < NCLASS) acc += v * bf2f(dense[(size_t)c * NCLASS + l]);
        }
    }
    float logit = (l < NCLASS) ? (acc + b2[l]) : -INFINITY;
    float m = logit;
    #pragma unroll
    for (int o = 32; o >= 1; o >>= 1) m = fmaxf(m, __shfl_xor(m, o, 64));
    float e = (l < NCLASS) ? __expf(logit - m) : 0.f;
    float s = e;
    #pragma unroll
    for (int o = 32; o >= 1; o >>= 1) s += __shfl_xor(s, o, 64);
    if (l < NCLASS) out[(size_t)r * NCLASS + l] = logit - m - __logf(s);
}

// ============================ launch ============================

extern "C" void kernel_launch(void* const* d_in, const int* in_sizes, int n_in,
                              void* d_out, int out_size, void* d_ws, size_t ws_size,
                              hipStream_t stream) {
    const float* x       = (const float*)d_in[0];
    const int*   adj_row = (const int*)d_in[1];
    const int*   adj_col = (const int*)d_in[2];
    const float* adj_val = (const float*)d_in[3];
    const float* W1      = (const float*)d_in[4];
    const float* b1      = (const float*)d_in[5];
    const float* W2      = (const float*)d_in[6];
    const float* b2      = (const float*)d_in[7];
    float* out = (float*)d_out;

    char* ws = (char*)d_ws;
    size_t off = 0;
    auto alloc = [&](size_t bytes) -> void* {
        void* p = ws + off;
        off += bytes;
        off = (off + 255) & ~(size_t)255;
        return p;
    };
    unsigned short* support1 = (unsigned short*)alloc((size_t)N_NODES * NHID * 2);   // 25.6 MB
    unsigned short* h        = (unsigned short*)alloc((size_t)N_NODES * NHID * 2);   // 25.6 MB
    unsigned short* support2 = (unsigned short*)alloc((size_t)N_NODES * NCLASS * 2); // 8 MB
    unsigned short* W1T      = (unsigned short*)alloc((size_t)NFEAT * NHID * 2);     // 128 KB
    int*   offsets   = (int*)alloc((size_t)(N_NODES + 4) * 4);
    int*   countsPad = (int*)alloc((size_t)N_NODES * CPAD * 4);                      // 6.4 MB
    int*   blockSums = (int*)alloc(1024 * 4);
    unsigned short* ranks = (unsigned short*)alloc((size_t)N_EDGES * 2);             // 3.2 MB
    int2*  csr       = (int2*)alloc((size_t)N_EDGES * 8);                            // 12.8 MB

    hipMemsetAsync(countsPad, 0, (size_t)N_NODES * CPAD * sizeof(int), stream);
    convert_W1_kernel<<<(NFEAT * NHID) / 256, 256, 0, stream>>>(W1, W1T);
    // fused GEMM1 + edge-count/rank
    fusedA_kernel<<<GEMM1_BLOCKS + COUNT_BLOCKS, 256, 0, stream>>>(
        x, W1T, support1, adj_row, countsPad, ranks);
    int nblk = (N_NODES + 1023) / 1024;   // 98
    scan1_kernel<<<nblk, 256, 0, stream>>>(countsPad, offsets, blockSums, N_NODES);
    scan2_kernel<<<1, 128, 0, stream>>>(blockSums, nblk);
    scan3_kernel<<<nblk, 256, 0, stream>>>(offsets, blockSums, N_NODES, N_EDGES);
    fill_kernel<<<COUNT_BLOCKS, 256, 0, stream>>>(adj_row, adj_col, adj_val,
                                                  offsets, ranks, csr);
    spmm1_kernel<<<N_NODES / 4, 256, 0, stream>>>(offsets, csr, support1, b1, h);
    gemm2_kernel<<<N_NODES / 32, 256, 0, stream>>>(h, W2, support2);
    spmm2_kernel<<<N_NODES / 4, 256, 0, stream>>>(offsets, csr, support2, b2, out);
}